// Round 9
// baseline (220.654 us; speedup 1.0000x reference)
//
#include <hip/hip_runtime.h>
#include <hip/hip_bf16.h>

// GATConv on gfx950.
// R9: csr_gat occupancy fix. R8: csr_gat=79us @ Occupancy 27% ran the SAME
// 146MB L2-miss gather that standalone gat did in 49.8us @ 64% occupancy
// (~3TB/s) -- latency-hiding-starved (391 blocks x 8 waves = 12 waves/CU,
// uneven packing), not BW-floored. Fix: BUCK 128->64 (1024 bins, dst>>6):
// csr_gat = 782 blocks (~24 waves/CU), stage 16KB, sort passes halved.
// Scatter counting-sort widened to 1024 bins (2-elem/thread scan).
// Structure (proven R8): prep | FUSED gemm+scatter (R0: overlap on disjoint
// CUs) | csr_gat (per 64-dst bin: LDS hist/scan/rank sort of ~2K edges,
// w=exp(lrelu(el[u]+er[d])) packed (bf16(w)<<16|src), no max-sub: |e|<~25
// << 88; then 8 waves x 8 dsts register-accum readlane gat from LDS).
// Fact bank: R5: random 4B global writes = 64B-line amplification, ~80us.
// R6: LDS atomics between gathers fence the load pipe (540cy/edge).
// R2/R4: gather is L2-miss-service-bound (~3TB/s), not VALU (scalarization
// VGPR 24->12 no delta). R8: FETCH_SIZE = L2-miss traffic, not pure HBM.

#define IN_FEATS 256
#define OUT_FEATS 128
#define NBINS 1024             // fine buckets (dst>>6); 782 used at N=50000
#define BUCK 64                // dsts per bucket
#define CAPB_LOG 12
#define CAPB (1 << CAPB_LOG)   // per-bin arena cap (mean 2046, sigma 45)
#define SORT_CAP 8192          // scatter chunk cap (E/256=6250)
#define SCAT_BLOCKS 256
#define BIN_STRIDE 16          // ints per bin cursor: 1 per 64B line

typedef __bf16 bf16x8 __attribute__((ext_vector_type(8)));
typedef float f32x4 __attribute__((ext_vector_type(4)));

__global__ void prep(const float* __restrict__ W, __bf16* __restrict__ Wb, int nw,
                     int* __restrict__ cur) {
    int i = blockIdx.x * 256 + threadIdx.x;
    if (i < nw) Wb[i] = (__bf16)W[i];
    if (i < NBINS) cur[i * BIN_STRIDE] = i << CAPB_LOG;
}

// ---------- FUSED: scatter blocks [0,S) + gemm blocks [S,S+G), 512 thr ----------
__global__ __launch_bounds__(512) void gemm_scatter(
    const float* __restrict__ feat, const __bf16* __restrict__ Wb,
    const float* __restrict__ attn_l, const float* __restrict__ attn_r,
    __bf16* __restrict__ hb, float* __restrict__ el, float* __restrict__ er,
    const int* __restrict__ src, const int* __restrict__ dst,
    int* __restrict__ bin_cur, unsigned* __restrict__ arena,
    int n, int E, int S) {
    __shared__ unsigned sorted[SORT_CAP];   // 32 KB bin-sorted chunk
    __shared__ int h[NBINS];                // 4 KB
    __shared__ int off[NBINS];              // 4 KB
    __shared__ int gbase[NBINS];            // 4 KB

    if (blockIdx.x < S) {
        // ---------------- scatter path (counting sort, 1024 bins) ----------------
        const int t = threadIdx.x;          // blockDim == 512; 2 bins/thread
        const int t2 = t + 512;
        const int chunk = (E + S - 1) / S;  // 6250
        const int beg = blockIdx.x * chunk;
        const int end = min(beg + chunk, E);

        h[t] = 0; h[t2] = 0;
        __syncthreads();
        for (int i = beg + t; i < end; i += 512)
            atomicAdd(&h[dst[i] >> 6], 1);             // LDS hist
        __syncthreads();

        off[t] = h[t]; off[t2] = h[t2];                // inclusive scan (1024)
        __syncthreads();
        for (int o = 1; o < NBINS; o <<= 1) {
            int v0 = (t >= o) ? off[t - o] : 0;
            int v1 = (t2 >= o) ? off[t2 - o] : 0;      // reads pre-barrier values
            __syncthreads();
            off[t] += v0; off[t2] += v1;
            __syncthreads();
        }
        const int c0 = h[t], c1 = h[t2];
        const int e0 = off[t] - c0, e1 = off[t2] - c1;
        __syncthreads();
        off[t] = e0; off[t2] = e1;                     // exclusive offsets
        if (c0 > 0) gbase[t] = atomicAdd(&bin_cur[t * BIN_STRIDE], c0);
        if (c1 > 0) gbase[t2] = atomicAdd(&bin_cur[t2 * BIN_STRIDE], c1);
        h[t] = 0; h[t2] = 0;
        __syncthreads();

        for (int i = beg + t; i < end; i += 512) {     // rank + place in LDS
            int d = dst[i];
            int bin = d >> 6;
            int r = atomicAdd(&h[bin], 1);
            sorted[off[bin] + r] = ((unsigned)d << 16) | (unsigned)src[i];
        }
        __syncthreads();

        const int tot = end - beg;                     // contiguous run writes
        for (int j = t; j < tot; j += 512) {
            unsigned w = sorted[j];
            int bin = w >> 22;                         // d>>6
            int pos = gbase[bin] + (j - off[bin]);
            pos = min(pos, ((bin + 1) << CAPB_LOG) - 1);
            arena[pos] = w;
        }
        return;
    }

    // ---------------- gemm path: 8 waves x 16 rows = 128 rows/block ----------------
    const int wid = threadIdx.x >> 6;
    const int lane = threadIdx.x & 63;
    const int s = lane & 15;
    const int q = lane >> 4;
    const int m0 = (blockIdx.x - S) * 128 + wid * 16;
    if (m0 >= n) return;

    const int mrow = min(m0 + s, n - 1);
    const float* arow = feat + (size_t)mrow * IN_FEATS + q * 8;

    f32x4 acc[8];
#pragma unroll
    for (int nt = 0; nt < 8; nt++) acc[nt] = (f32x4){0.f, 0.f, 0.f, 0.f};

#pragma unroll
    for (int ks = 0; ks < 8; ks++) {
        const int k0 = ks * 32;
        float4 f0 = *(const float4*)(arow + k0);
        float4 f1 = *(const float4*)(arow + k0 + 4);
        bf16x8 a;
        a[0] = (__bf16)f0.x; a[1] = (__bf16)f0.y; a[2] = (__bf16)f0.z; a[3] = (__bf16)f0.w;
        a[4] = (__bf16)f1.x; a[5] = (__bf16)f1.y; a[6] = (__bf16)f1.z; a[7] = (__bf16)f1.w;
#pragma unroll
        for (int nt = 0; nt < 8; nt++) {
            bf16x8 b = *(const bf16x8*)(Wb + (size_t)(nt * 16 + s) * IN_FEATS + k0 + q * 8);
            acc[nt] = __builtin_amdgcn_mfma_f32_16x16x32_bf16(a, b, acc[nt], 0, 0, 0);
        }
    }

    float al[8], ar[8];
#pragma unroll
    for (int nt = 0; nt < 8; nt++) {
        al[nt] = attn_l[nt * 16 + s];
        ar[nt] = attn_r[nt * 16 + s];
    }

#pragma unroll
    for (int r = 0; r < 4; r++) {
        const int row = m0 + q * 4 + r;
        const bool ok = row < n;
        float pl = 0.f, pr = 0.f;
#pragma unroll
        for (int nt = 0; nt < 8; nt++) {
            float v = acc[nt][r];
            if (ok) hb[(size_t)row * OUT_FEATS + nt * 16 + s] = (__bf16)v;
            pl += v * al[nt];
            pr += v * ar[nt];
        }
#pragma unroll
        for (int m = 1; m < 16; m <<= 1) {
            pl += __shfl_xor(pl, m);
            pr += __shfl_xor(pr, m);
        }
        if (ok && s == 0) {
            el[row] = pl;
            er[row] = pr;
        }
    }
}

// ---- csr_gat: one block per 64-dst bin: LDS sort, then register-accum gat ----
__global__ __launch_bounds__(512) void csr_gat(
    const unsigned* __restrict__ arena, const int* __restrict__ bin_cur,
    const float* __restrict__ el, const float* __restrict__ er,
    const __bf16* __restrict__ hb, float* __restrict__ out, int N) {
    __shared__ unsigned stage[CAPB];     // 16 KB dst-sorted packed edges
    __shared__ int cnt[BUCK];
    __shared__ int off[BUCK];
    __shared__ float erl[BUCK];
    const int b = blockIdx.x;
    const int t = threadIdx.x;
    const int abeg = b << CAPB_LOG;
    const int cin = min(bin_cur[b * BIN_STRIDE] - abeg, CAPB);
    const int d0 = b * BUCK;

    if (t < BUCK) {
        cnt[t] = 0;
        erl[t] = (d0 + t < N) ? er[d0 + t] : 0.f;
    }
    __syncthreads();

    // pass 1: sub-bin histogram (coalesced arena read)
    for (int i = t; i < cin; i += 512)
        atomicAdd(&cnt[(arena[abeg + i] >> 16) & (BUCK - 1)], 1);
    __syncthreads();
    if (t < BUCK) off[t] = cnt[t];
    __syncthreads();
    for (int o = 1; o < BUCK; o <<= 1) {           // inclusive scan (64)
        int v = (t < BUCK && t >= o) ? off[t - o] : 0;
        __syncthreads();
        if (t < BUCK) off[t] += v;
        __syncthreads();
    }
    if (t < BUCK) {
        off[t] -= cnt[t];                          // exclusive offsets
        cnt[t] = 0;
    }
    __syncthreads();

    // pass 2: weight + rank into dst-sorted LDS stage (arena re-read L2-hot)
    for (int i = t; i < cin; i += 512) {
        unsigned e = arena[abeg + i];
        int d6 = (e >> 16) & (BUCK - 1);
        int u = (int)(e & 0xFFFFu);
        float x = el[u] + erl[d6];                 // el: 200KB random, L2
        x = (x > 0.f) ? x : 0.2f * x;
        float w = __expf(x);
        int r = atomicAdd(&cnt[d6], 1);            // after this, cnt[d6]==deg
        stage[off[d6] + r] = (__float_as_uint(w) & 0xFFFF0000u) | (unsigned)u;
    }
    __syncthreads();

    // gat phase: 8 waves x 8 dsts, register accumulation (proven pattern)
    const int wid = t >> 6;
    const int lane = t & 63;
    const unsigned* hbu = (const unsigned*)hb;
#pragma unroll 1
    for (int j = 0; j < BUCK / 8; j++) {
        const int d6 = wid * (BUCK / 8) + j;
        const int v = d0 + d6;
        if (v >= N) break;                         // tail bucket only
        const int rbeg = __builtin_amdgcn_readfirstlane(off[d6]);
        const int deg  = __builtin_amdgcn_readfirstlane(cnt[d6]);
        float acc0 = 0.f, acc1 = 0.f, wsum = 0.f;
        for (int c0 = rbeg; c0 < rbeg + deg; c0 += 64) {
            const int nn = min(64, rbeg + deg - c0);
            unsigned my = (lane < nn) ? stage[c0 + lane] : 0u;
            int k = 0;
            for (; k + 8 <= nn; k += 8) {
#pragma unroll
                for (int tt = 0; tt < 8; tt++) {
                    const unsigned es = (unsigned)__builtin_amdgcn_readlane((int)my, k + tt);
                    const unsigned us = es & 0xFFFFu;
                    const float ws = __uint_as_float(es & 0xFFFF0000u);
                    const unsigned pair = hbu[(size_t)us * (OUT_FEATS / 2) + lane];
                    wsum += ws;
                    acc0 += ws * __uint_as_float(pair << 16);
                    acc1 += ws * __uint_as_float(pair & 0xffff0000u);
                }
            }
            for (; k < nn; k++) {
                const unsigned es = (unsigned)__builtin_amdgcn_readlane((int)my, k);
                const unsigned us = es & 0xFFFFu;
                const float ws = __uint_as_float(es & 0xFFFF0000u);
                const unsigned pair = hbu[(size_t)us * (OUT_FEATS / 2) + lane];
                wsum += ws;
                acc0 += ws * __uint_as_float(pair << 16);
                acc1 += ws * __uint_as_float(pair & 0xffff0000u);
            }
        }
        const float dnm = fmaxf(wsum, 1e-9f);
        float2 o = make_float2(acc0 / dnm, acc1 / dnm);
        *(float2*)(out + (size_t)v * OUT_FEATS + lane * 2) = o;
    }
}

extern "C" void kernel_launch(void* const* d_in, const int* in_sizes, int n_in,
                              void* d_out, int out_size, void* d_ws, size_t ws_size,
                              hipStream_t stream) {
    const float* feat   = (const float*)d_in[0];
    const float* W      = (const float*)d_in[1];
    const float* attn_l = (const float*)d_in[2];
    const float* attn_r = (const float*)d_in[3];
    const int*   src    = (const int*)d_in[4];
    const int*   dst    = (const int*)d_in[5];
    const int N = in_sizes[0] / IN_FEATS;
    const int E = in_sizes[4];
    float* out = (float*)d_out;

    char* p = (char*)d_ws;
    auto alloc = [&](size_t bytes) -> char* {
        char* r = p;
        p += (bytes + 255) & ~(size_t)255;
        return r;
    };
    const int nbuckets = (N + BUCK - 1) / BUCK;    // 782

    __bf16* hb      = (__bf16*)alloc((size_t)N * OUT_FEATS * sizeof(__bf16));
    __bf16* Wb      = (__bf16*)alloc((size_t)OUT_FEATS * IN_FEATS * sizeof(__bf16));
    float*  el      = (float*)alloc((size_t)N * sizeof(float));
    float*  er      = (float*)alloc((size_t)N * sizeof(float));
    int*    bin_cur = (int*)alloc((size_t)NBINS * BIN_STRIDE * sizeof(int));
    unsigned* arena = (unsigned*)alloc((size_t)NBINS * CAPB * sizeof(unsigned));

    const int nw = OUT_FEATS * IN_FEATS;           // 32768 (covers NBINS init)
    prep<<<dim3((nw + 255) / 256), dim3(256), 0, stream>>>(W, Wb, nw, bin_cur);

    const int G = (N + 127) / 128;                 // 391 gemm blocks
    gemm_scatter<<<dim3(SCAT_BLOCKS + G), dim3(512), 0, stream>>>(
        feat, Wb, attn_l, attn_r, hb, el, er, src, dst, bin_cur, arena, N, E,
        SCAT_BLOCKS);

    csr_gat<<<dim3(nbuckets), dim3(512), 0, stream>>>(arena, bin_cur, el, er,
                                                      hb, out, N);
}

// Round 10
// 218.587 us; speedup vs baseline: 1.0095x; 1.0095x over previous
//
#include <hip/hip_runtime.h>
#include <hip/hip_bf16.h>

// GATConv on gfx950.
// R10: TLP restore for the fused kernel. R9: gemm_scatter=73.5us @ 23% occ
// (647 blocks x 512thr, 44KB LDS ~ 2.5 blocks/CU) vs R0's 66.1us @ 28% occ
// (1294 x 256thr ~ 5 blocks/CU). Both paths are latency-bound (MFMA 1.6% =
// exactly the 3.3GF/73.5us ratio -> compute irrelevant); wall ~ latency/TLP.
// Fix: 256-thr blocks; gemm = R0's proven 64-row/4-wave path (782 blocks);
// scatter = 512 blocks, chunk 3125, 1024-bin LDS counting sort in 29KB
// (SORT_CAP 4096; 4-bin/thread scan: thread totals -> 8-round scan -> local
// prefix) -> 5 blocks/CU. csr_gat IDENTICAL to R9 (BUCK=64, 782 blocks;
// R9 dropped it below 73us from R8's 79).
// Fact bank: R5: random 4B global writes = 64B-line write amplification
// (103MB for 6.4MB payload, ~80us) -- arena writes stay run-contiguous.
// R6: LDS atomics interleaved with gathers fence the load pipe. R2/R4: hb
// gather is L2-miss-service-bound ~3TB/s (146MB), not VALU. R8: csr_gat
// occupancy starvation costs 40% on the same gather.

#define IN_FEATS 256
#define OUT_FEATS 128
#define NBINS 1024             // fine buckets (dst>>6); 782 used at N=50000
#define BUCK 64                // dsts per bucket
#define CAPB_LOG 12
#define CAPB (1 << CAPB_LOG)   // per-bin arena cap (mean 2046, sigma 45)
#define SORT_CAP 4096          // scatter chunk cap (E/512=3125)
#define SCAT_BLOCKS 512
#define BIN_STRIDE 16          // ints per bin cursor: 1 per 64B line

typedef __bf16 bf16x8 __attribute__((ext_vector_type(8)));
typedef float f32x4 __attribute__((ext_vector_type(4)));

__global__ void prep(const float* __restrict__ W, __bf16* __restrict__ Wb, int nw,
                     int* __restrict__ cur) {
    int i = blockIdx.x * 256 + threadIdx.x;
    if (i < nw) Wb[i] = (__bf16)W[i];
    if (i < NBINS) cur[i * BIN_STRIDE] = i << CAPB_LOG;
}

// ---------- FUSED: gemm blocks [0,G) + scatter blocks [G,G+512), 256 thr ----------
__global__ __launch_bounds__(256) void gemm_scatter(
    const float* __restrict__ feat, const __bf16* __restrict__ Wb,
    const float* __restrict__ attn_l, const float* __restrict__ attn_r,
    __bf16* __restrict__ hb, float* __restrict__ el, float* __restrict__ er,
    const int* __restrict__ src, const int* __restrict__ dst,
    int* __restrict__ bin_cur, unsigned* __restrict__ arena,
    int n, int E, int G) {
    __shared__ unsigned sorted[SORT_CAP];   // 16 KB bin-sorted chunk
    __shared__ int h[NBINS];                // 4 KB
    __shared__ int off[NBINS];              // 4 KB
    __shared__ int gbase[NBINS];            // 4 KB
    __shared__ int sblk[256];               // 1 KB scan buffer

    if (blockIdx.x >= G) {
        // ---------------- scatter path (counting sort, 1024 bins) ----------------
        const int t = threadIdx.x;          // 256 threads; 4 bins/thread
        const int blk = blockIdx.x - G;
        const int chunk = (E + SCAT_BLOCKS - 1) / SCAT_BLOCKS;  // 3125
        const int beg = blk * chunk;
        const int end = min(beg + chunk, E);

        h[4 * t] = 0; h[4 * t + 1] = 0; h[4 * t + 2] = 0; h[4 * t + 3] = 0;
        __syncthreads();
        for (int i = beg + t; i < end; i += 256)
            atomicAdd(&h[dst[i] >> 6], 1);             // LDS hist
        __syncthreads();

        // 4-bin/thread exclusive scan: thread totals -> 256-scan -> local prefix
        const int a0 = h[4 * t], a1 = h[4 * t + 1], a2 = h[4 * t + 2], a3 = h[4 * t + 3];
        const int tot = a0 + a1 + a2 + a3;
        sblk[t] = tot;
        __syncthreads();
        for (int o = 1; o < 256; o <<= 1) {
            int v = (t >= o) ? sblk[t - o] : 0;
            __syncthreads();
            sblk[t] += v;
            __syncthreads();
        }
        const int base = sblk[t] - tot;                // exclusive over threads
        off[4 * t] = base;
        off[4 * t + 1] = base + a0;
        off[4 * t + 2] = base + a0 + a1;
        off[4 * t + 3] = base + a0 + a1 + a2;
        if (a0 > 0) gbase[4 * t]     = atomicAdd(&bin_cur[(4 * t) * BIN_STRIDE], a0);
        if (a1 > 0) gbase[4 * t + 1] = atomicAdd(&bin_cur[(4 * t + 1) * BIN_STRIDE], a1);
        if (a2 > 0) gbase[4 * t + 2] = atomicAdd(&bin_cur[(4 * t + 2) * BIN_STRIDE], a2);
        if (a3 > 0) gbase[4 * t + 3] = atomicAdd(&bin_cur[(4 * t + 3) * BIN_STRIDE], a3);
        h[4 * t] = 0; h[4 * t + 1] = 0; h[4 * t + 2] = 0; h[4 * t + 3] = 0;
        __syncthreads();

        for (int i = beg + t; i < end; i += 256) {     // rank + place in LDS
            int d = dst[i];
            int bin = d >> 6;
            int r = atomicAdd(&h[bin], 1);
            sorted[off[bin] + r] = ((unsigned)d << 16) | (unsigned)src[i];
        }
        __syncthreads();

        const int tot2 = end - beg;                    // contiguous run writes
        for (int j = t; j < tot2; j += 256) {
            unsigned w = sorted[j];
            int bin = w >> 22;                         // d>>6
            int pos = gbase[bin] + (j - off[bin]);
            pos = min(pos, ((bin + 1) << CAPB_LOG) - 1);
            arena[pos] = w;
        }
        return;
    }

    // ---------------- gemm path: 4 waves x 16 rows = 64 rows/block (R0) ----------------
    const int wid = threadIdx.x >> 6;
    const int lane = threadIdx.x & 63;
    const int s = lane & 15;
    const int q = lane >> 4;
    const int m0 = blockIdx.x * 64 + wid * 16;
    if (m0 >= n) return;

    const int mrow = min(m0 + s, n - 1);
    const float* arow = feat + (size_t)mrow * IN_FEATS + q * 8;

    f32x4 acc[8];
#pragma unroll
    for (int nt = 0; nt < 8; nt++) acc[nt] = (f32x4){0.f, 0.f, 0.f, 0.f};

#pragma unroll
    for (int ks = 0; ks < 8; ks++) {
        const int k0 = ks * 32;
        float4 f0 = *(const float4*)(arow + k0);
        float4 f1 = *(const float4*)(arow + k0 + 4);
        bf16x8 a;
        a[0] = (__bf16)f0.x; a[1] = (__bf16)f0.y; a[2] = (__bf16)f0.z; a[3] = (__bf16)f0.w;
        a[4] = (__bf16)f1.x; a[5] = (__bf16)f1.y; a[6] = (__bf16)f1.z; a[7] = (__bf16)f1.w;
#pragma unroll
        for (int nt = 0; nt < 8; nt++) {
            bf16x8 b = *(const bf16x8*)(Wb + (size_t)(nt * 16 + s) * IN_FEATS + k0 + q * 8);
            acc[nt] = __builtin_amdgcn_mfma_f32_16x16x32_bf16(a, b, acc[nt], 0, 0, 0);
        }
    }

    float al[8], ar[8];
#pragma unroll
    for (int nt = 0; nt < 8; nt++) {
        al[nt] = attn_l[nt * 16 + s];
        ar[nt] = attn_r[nt * 16 + s];
    }

#pragma unroll
    for (int r = 0; r < 4; r++) {
        const int row = m0 + q * 4 + r;
        const bool ok = row < n;
        float pl = 0.f, pr = 0.f;
#pragma unroll
        for (int nt = 0; nt < 8; nt++) {
            float v = acc[nt][r];
            if (ok) hb[(size_t)row * OUT_FEATS + nt * 16 + s] = (__bf16)v;
            pl += v * al[nt];
            pr += v * ar[nt];
        }
#pragma unroll
        for (int m = 1; m < 16; m <<= 1) {
            pl += __shfl_xor(pl, m);
            pr += __shfl_xor(pr, m);
        }
        if (ok && s == 0) {
            el[row] = pl;
            er[row] = pr;
        }
    }
}

// ---- csr_gat: one block per 64-dst bin (IDENTICAL to R9) ----
__global__ __launch_bounds__(512) void csr_gat(
    const unsigned* __restrict__ arena, const int* __restrict__ bin_cur,
    const float* __restrict__ el, const float* __restrict__ er,
    const __bf16* __restrict__ hb, float* __restrict__ out, int N) {
    __shared__ unsigned stage[CAPB];     // 16 KB dst-sorted packed edges
    __shared__ int cnt[BUCK];
    __shared__ int off[BUCK];
    __shared__ float erl[BUCK];
    const int b = blockIdx.x;
    const int t = threadIdx.x;
    const int abeg = b << CAPB_LOG;
    const int cin = min(bin_cur[b * BIN_STRIDE] - abeg, CAPB);
    const int d0 = b * BUCK;

    if (t < BUCK) {
        cnt[t] = 0;
        erl[t] = (d0 + t < N) ? er[d0 + t] : 0.f;
    }
    __syncthreads();

    // pass 1: sub-bin histogram (coalesced arena read)
    for (int i = t; i < cin; i += 512)
        atomicAdd(&cnt[(arena[abeg + i] >> 16) & (BUCK - 1)], 1);
    __syncthreads();
    if (t < BUCK) off[t] = cnt[t];
    __syncthreads();
    for (int o = 1; o < BUCK; o <<= 1) {           // inclusive scan (64)
        int v = (t < BUCK && t >= o) ? off[t - o] : 0;
        __syncthreads();
        if (t < BUCK) off[t] += v;
        __syncthreads();
    }
    if (t < BUCK) {
        off[t] -= cnt[t];                          // exclusive offsets
        cnt[t] = 0;
    }
    __syncthreads();

    // pass 2: weight + rank into dst-sorted LDS stage (arena re-read L2-hot)
    for (int i = t; i < cin; i += 512) {
        unsigned e = arena[abeg + i];
        int d6 = (e >> 16) & (BUCK - 1);
        int u = (int)(e & 0xFFFFu);
        float x = el[u] + erl[d6];                 // el: 200KB random, L2
        x = (x > 0.f) ? x : 0.2f * x;
        float w = __expf(x);
        int r = atomicAdd(&cnt[d6], 1);            // after this, cnt[d6]==deg
        stage[off[d6] + r] = (__float_as_uint(w) & 0xFFFF0000u) | (unsigned)u;
    }
    __syncthreads();

    // gat phase: 8 waves x 8 dsts, register accumulation (proven pattern)
    const int wid = t >> 6;
    const int lane = t & 63;
    const unsigned* hbu = (const unsigned*)hb;
#pragma unroll 1
    for (int j = 0; j < BUCK / 8; j++) {
        const int d6 = wid * (BUCK / 8) + j;
        const int v = d0 + d6;
        if (v >= N) break;                         // tail bucket only
        const int rbeg = __builtin_amdgcn_readfirstlane(off[d6]);
        const int deg  = __builtin_amdgcn_readfirstlane(cnt[d6]);
        float acc0 = 0.f, acc1 = 0.f, wsum = 0.f;
        for (int c0 = rbeg; c0 < rbeg + deg; c0 += 64) {
            const int nn = min(64, rbeg + deg - c0);
            unsigned my = (lane < nn) ? stage[c0 + lane] : 0u;
            int k = 0;
            for (; k + 8 <= nn; k += 8) {
#pragma unroll
                for (int tt = 0; tt < 8; tt++) {
                    const unsigned es = (unsigned)__builtin_amdgcn_readlane((int)my, k + tt);
                    const unsigned us = es & 0xFFFFu;
                    const float ws = __uint_as_float(es & 0xFFFF0000u);
                    const unsigned pair = hbu[(size_t)us * (OUT_FEATS / 2) + lane];
                    wsum += ws;
                    acc0 += ws * __uint_as_float(pair << 16);
                    acc1 += ws * __uint_as_float(pair & 0xffff0000u);
                }
            }
            for (; k < nn; k++) {
                const unsigned es = (unsigned)__builtin_amdgcn_readlane((int)my, k);
                const unsigned us = es & 0xFFFFu;
                const float ws = __uint_as_float(es & 0xFFFF0000u);
                const unsigned pair = hbu[(size_t)us * (OUT_FEATS / 2) + lane];
                wsum += ws;
                acc0 += ws * __uint_as_float(pair << 16);
                acc1 += ws * __uint_as_float(pair & 0xffff0000u);
            }
        }
        const float dnm = fmaxf(wsum, 1e-9f);
        float2 o = make_float2(acc0 / dnm, acc1 / dnm);
        *(float2*)(out + (size_t)v * OUT_FEATS + lane * 2) = o;
    }
}

extern "C" void kernel_launch(void* const* d_in, const int* in_sizes, int n_in,
                              void* d_out, int out_size, void* d_ws, size_t ws_size,
                              hipStream_t stream) {
    const float* feat   = (const float*)d_in[0];
    const float* W      = (const float*)d_in[1];
    const float* attn_l = (const float*)d_in[2];
    const float* attn_r = (const float*)d_in[3];
    const int*   src    = (const int*)d_in[4];
    const int*   dst    = (const int*)d_in[5];
    const int N = in_sizes[0] / IN_FEATS;
    const int E = in_sizes[4];
    float* out = (float*)d_out;

    char* p = (char*)d_ws;
    auto alloc = [&](size_t bytes) -> char* {
        char* r = p;
        p += (bytes + 255) & ~(size_t)255;
        return r;
    };
    const int nbuckets = (N + BUCK - 1) / BUCK;    // 782

    __bf16* hb      = (__bf16*)alloc((size_t)N * OUT_FEATS * sizeof(__bf16));
    __bf16* Wb      = (__bf16*)alloc((size_t)OUT_FEATS * IN_FEATS * sizeof(__bf16));
    float*  el      = (float*)alloc((size_t)N * sizeof(float));
    float*  er      = (float*)alloc((size_t)N * sizeof(float));
    int*    bin_cur = (int*)alloc((size_t)NBINS * BIN_STRIDE * sizeof(int));
    unsigned* arena = (unsigned*)alloc((size_t)NBINS * CAPB * sizeof(unsigned));

    const int nw = OUT_FEATS * IN_FEATS;           // 32768 (covers NBINS init)
    prep<<<dim3((nw + 255) / 256), dim3(256), 0, stream>>>(W, Wb, nw, bin_cur);

    const int G = (N + 63) / 64;                   // 782 gemm blocks
    gemm_scatter<<<dim3(G + SCAT_BLOCKS), dim3(256), 0, stream>>>(
        feat, Wb, attn_l, attn_r, hb, el, er, src, dst, bin_cur, arena, N, E, G);

    csr_gat<<<dim3(nbuckets), dim3(512), 0, stream>>>(arena, bin_cur, el, er,
                                                      hb, out, N);
}